// Round 12
// baseline (56.616 us; speedup 1.0000x reference)
//
#include <hip/hip_runtime.h>
#include <cstdint>

static constexpr int Bc = 32, Tc = 128, Fc = 32, Hc = 4, HDc = 16, RKc = 16;
static constexpr int Nc = Tc * Fc;  // 4096
static constexpr int WS36 = 36;     // row-major [*][32] padded stride
static constexpr int TS = 132;      // transposed [32][128] padded stride
static constexpr int TAS = 132;     // ta LDS row stride

__device__ __forceinline__ uint32_t rotl32(uint32_t v, int r) {
  return (v << r) | (v >> (32 - r));
}

__device__ __forceinline__ void threefry2x32(uint32_t k0, uint32_t k1,
                                             uint32_t& x0, uint32_t& x1) {
  uint32_t k2 = k0 ^ k1 ^ 0x1BD11BDAu;
  x0 += k0; x1 += k1;
#define TF_R(r) { x0 += x1; x1 = rotl32(x1, (r)); x1 ^= x0; }
  TF_R(13) TF_R(15) TF_R(26) TF_R(6)
  x0 += k1; x1 += k2 + 1u;
  TF_R(17) TF_R(29) TF_R(16) TF_R(24)
  x0 += k2; x1 += k0 + 2u;
  TF_R(13) TF_R(15) TF_R(26) TF_R(6)
  x0 += k0; x1 += k1 + 3u;
  TF_R(17) TF_R(29) TF_R(16) TF_R(24)
  x0 += k1; x1 += k2 + 4u;
  TF_R(13) TF_R(15) TF_R(26) TF_R(6)
  x0 += k2; x1 += k0 + 5u;
#undef TF_R
}

// XLA ErfInv32; __logf (v_log_f32) — rel err ~1e-6, harmless for v0/sn.
__device__ __forceinline__ float erfinv_f32(float x) {
  float w = -__logf((1.0f - x) * (1.0f + x));
  float p;
  if (w < 5.0f) {
    w -= 2.5f;
    p = 2.81022636e-08f;
    p = fmaf(p, w, 3.43273939e-07f);
    p = fmaf(p, w, -3.5233877e-06f);
    p = fmaf(p, w, -4.39150654e-06f);
    p = fmaf(p, w, 0.00021858087f);
    p = fmaf(p, w, -0.00125372503f);
    p = fmaf(p, w, -0.00417768164f);
    p = fmaf(p, w, 0.246640727f);
    p = fmaf(p, w, 1.50140941f);
  } else {
    w = sqrtf(w) - 3.0f;
    p = -0.000200214257f;
    p = fmaf(p, w, 0.000100950558f);
    p = fmaf(p, w, 0.00134934322f);
    p = fmaf(p, w, -0.00367342844f);
    p = fmaf(p, w, 0.00573950773f);
    p = fmaf(p, w, -0.0076224613f);
    p = fmaf(p, w, 0.00943887047f);
    p = fmaf(p, w, 1.00167406f);
    p = fmaf(p, w, 2.83297682f);
  }
  return p * x;
}

__device__ __forceinline__ float jax_normal_from_bits(uint32_t bits) {
  const float lo = -0.99999994f;
  float f = __uint_as_float((bits >> 9) | 0x3f800000u) - 1.0f;
  float u = fmaxf(lo, f * 2.0f + lo);
  return 1.41421354f * erfinv_f32(u);
}

// ---------------------------------------------------------------------------
// Single kernel: grid (b, h) = (32, 4), 512 threads (8 waves -> 2/SIMD).
// Each block redundantly computes its head's ta (scores+softmax+threshold,
// dense in LDS), fa, PRNG v0, power iteration -> sn, then the Chebyshev conv
// for its batch. No workspace, no inter-kernel dependency.
// ---------------------------------------------------------------------------
__global__ __launch_bounds__(512, 1)
void fused_all_kernel(const float* __restrict__ x, const float* __restrict__ weight,
                      const float* __restrict__ bias, const float* __restrict__ tqg,
                      const float* __restrict__ tkg, const float* __restrict__ ffg,
                      float* __restrict__ out) {
  const int b = blockIdx.x, h = blockIdx.y;
  const int tid = (int)threadIdx.x;
  const int lane = tid & 63, wvi = tid >> 6;   // 8 waves

  __shared__ __align__(16) float taL[Tc * TAS];     // scores -> thresholded ta
  __shared__ __align__(16) float regB[8448];        // kS[4096]+qS[4096] -> ZT+XT
  __shared__ __align__(16) float bufRow[Tc * WS36]; // pi w -> Zs -> GT
  __shared__ __align__(16) float faS[Fc * WS36];    // fa[f1][f2]
  __shared__ __align__(16) float faTS[Fc * WS36];   // faT[f2][f1]
  __shared__ __align__(16) float W0s[Fc * HDc];
  __shared__ __align__(16) float W1s[Fc * HDc];
  __shared__ float wqv[Fc], wkv[Fc];
  __shared__ float rsT[Tc], rsF[Fc], red[8];
  __shared__ int flagS;

  float* kS = regB;                // [b][t] = b*128+t  (phase 1-2)
  float* qS = regB + 4096;         // [b][t]
  float* bufT = regB;              // ZT / pi wT  [f][t] stride TS (phase 3+)
  float* XT   = regB + 4224;       // [f][t] stride TS

  // ============ phase 0: wq/wk, W, fa, PRNG, early x->reg loads ============
  const float* xb = x + (size_t)b * Nc;
  const int xrow0 = tid >> 3, xc4 = tid & 7;
  float4 xv4a = *(const float4*)&xb[xrow0 * Fc + 4 * xc4];
  float4 xv4b = *(const float4*)&xb[(xrow0 + 64) * Fc + 4 * xc4];

  if (tid < Fc) {
    const float* W0 = weight + h * (Fc * HDc);
    float aq = 0.f, ak = 0.f;
    for (int d = 0; d < HDc; ++d) {
      float w0 = W0[tid * HDc + d];
      aq += w0 * tqg[h * HDc + d];
      ak += w0 * tkg[h * HDc + d];
    }
    wqv[tid] = aq; wkv[tid] = ak;
  }
  if (tid < Fc * HDc) {
    W0s[tid] = weight[h * (Fc * HDc) + tid];
    W1s[tid] = weight[(Hc + h) * (Fc * HDc) + tid];
  }
  // fa = threshold(softmax(leaky_relu(U V^T), axis=1)); 2 cells/thread
  for (int j2 = tid; j2 < Fc * Fc; j2 += 512) {
    const float* U = ffg + h * (2 * Fc * RKc);
    const float* V = U + Fc * RKc;
    int f1 = j2 >> 5, f2 = j2 & 31;
    float acc = 0.f;
    for (int r = 0; r < RKc; ++r) acc += U[f1 * RKc + r] * V[f2 * RKc + r];
    float val = fmaxf(acc, 0.2f * acc);
    float m = val;
    for (int o = 16; o > 0; o >>= 1) m = fmaxf(m, __shfl_xor(m, o, 32));
    float e = expf(val - m), se = e;
    for (int o = 16; o > 0; o >>= 1) se += __shfl_xor(se, o, 32);
    float pv = e / se;
    pv = (pv > 0.01f && f1 != f2) ? pv : 0.f;
    faS[f1 * WS36 + f2] = pv;
    faTS[f2 * WS36 + f1] = pv;
    float rsum = pv;
    for (int o = 16; o > 0; o >>= 1) rsum += __shfl_xor(rsum, o, 32);
    if (f2 == 0) rsF[f1] = rsum;
  }
  // PRNG v0 for pi map: rows {t, t+64}, cols f0..f0+3
  const int t = tid & 63, f0 = 4 * (tid >> 6);
  float v_reg[2][4], s_reg[2][4], nv[2][4];
  {
    uint32_t fk0 = 0u, fk1 = (uint32_t)h;
    threefry2x32(0u, 42u, fk0, fk1);
#pragma unroll
    for (int j = 0; j < 4; ++j) {
      int l = t * Fc + f0 + j;  // < 2048
      uint32_t c0 = (uint32_t)l, c1 = (uint32_t)(l + 2048);
      threefry2x32(fk0, fk1, c0, c1);
      v_reg[0][j] = jax_normal_from_bits(c0);   // (t, f)
      v_reg[1][j] = jax_normal_from_bits(c1);   // (t+64, f)
    }
  }
  __syncthreads();  // wqv/wkv ready

  // ============ phase 1: q/k projections for all (b,t) ============
  for (int i = tid; i < Bc * Tc; i += 512) {
    const float4* xr = (const float4*)(x + (size_t)i * Fc);
    float ak = 0.f, aq = 0.f;
#pragma unroll
    for (int j = 0; j < 8; ++j) {
      float4 v = xr[j];
      ak += v.x * wkv[4*j] + v.y * wkv[4*j+1] + v.z * wkv[4*j+2] + v.w * wkv[4*j+3];
      aq += v.x * wqv[4*j] + v.y * wqv[4*j+1] + v.z * wqv[4*j+2] + v.w * wqv[4*j+3];
    }
    kS[i] = ak;
    qS[i] = aq;
  }
  __syncthreads();

  // ============ phase 2: scores + row softmax + threshold -> taL, rsT ============
  {
    const int g = tid >> 5, l = tid & 31;   // 16 groups x 32 lanes
    for (int rr = 0; rr < 8; ++rr) {
      const int r = g + 16 * rr;
      float acc[4] = {};
      for (int bb = 0; bb < Bc; ++bb) {
        float q = qS[bb * Tc + r];
        float4 k4 = *(const float4*)&kS[bb * Tc + 4 * l];
#pragma unroll
        for (int j = 0; j < 4; ++j) {
          float s = q + ((const float*)&k4)[j];
          acc[j] += fmaxf(s, 0.2f * s);
        }
      }
#pragma unroll
      for (int j = 0; j < 4; ++j) acc[j] *= (1.0f / 32.0f);
      float m = fmaxf(fmaxf(acc[0], acc[1]), fmaxf(acc[2], acc[3]));
      for (int o = 16; o > 0; o >>= 1) m = fmaxf(m, __shfl_xor(m, o, 32));
      float e[4], se = 0.f;
#pragma unroll
      for (int j = 0; j < 4; ++j) { e[j] = expf(acc[j] - m); se += e[j]; }
      for (int o = 16; o > 0; o >>= 1) se += __shfl_xor(se, o, 32);
      float p[4]; float rs = 0.f;
#pragma unroll
      for (int j = 0; j < 4; ++j) {
        float pv = e[j] / se;
        int col = 4 * l + j;
        p[j] = ((pv > 0.01f) && (col != r)) ? pv : 0.f;
        rs += p[j];
      }
      for (int o = 16; o > 0; o >>= 1) rs += __shfl_xor(rs, o, 32);
      *(float4*)&taL[r * TAS + 4 * l] = make_float4(p[0], p[1], p[2], p[3]);
      if (l == 0) rsT[r] = rs;
    }
  }
  __syncthreads();

  // ============ phase 3: flag, s_reg, w init ============
  if (tid < 64) {
    int nz = (rsT[tid] > 0.f) || (rsT[tid + 64] > 0.f);
    unsigned long long bal = __ballot(nz);
    if (tid == 0) flagS = (bal != 0ull) ? 1 : 0;
  }
#pragma unroll
  for (int r = 0; r < 2; ++r) {
    float rrow = rsT[t + 64 * r];
#pragma unroll
    for (int j = 0; j < 4; ++j)
      s_reg[r][j] = 1.0f / sqrtf(rrow + rsF[f0 + j] + 1.0f + 1e-10f);
  }
#pragma unroll
  for (int r = 0; r < 2; ++r) {
    int row = t + 64 * r;
    float w[4];
#pragma unroll
    for (int j = 0; j < 4; ++j) w[j] = s_reg[r][j] * v_reg[r][j];
    *(float4*)&bufRow[row * WS36 + f0] = make_float4(w[0], w[1], w[2], w[3]);
#pragma unroll
    for (int j = 0; j < 4; ++j) bufT[(f0 + j) * TS + row] = w[j];
  }
  __syncthreads();  // w, flagS visible

  // ============ phase 4: power iteration (4 iters, Rayleigh on last) ============
  float snv = 1.0f;
  for (int it = 0; it < 4; ++it) {
    float acc[2][4] = {};
    if (flagS) {  // M1 dense from LDS ta (rare path)
#pragma unroll
      for (int r = 0; r < 2; ++r) {
        int row = t + 64 * r;
        for (int k = 0; k < Tc; ++k) {
          float ta = taL[row * TAS + k];
          float4 w4 = *(const float4*)&bufRow[k * WS36 + f0];  // broadcast
          acc[r][0] += ta * w4.x; acc[r][1] += ta * w4.y;
          acc[r][2] += ta * w4.z; acc[r][3] += ta * w4.w;
        }
      }
    }
    // M2: sum_f2 fa[f][f2] * w[row][f2]
    for (int f2 = 0; f2 < Fc; ++f2) {
      float4 fav = *(const float4*)&faTS[f2 * WS36 + f0];  // broadcast
      float w0 = bufT[f2 * TS + t];                        // lane-consecutive
      float w1 = bufT[f2 * TS + t + 64];
      acc[0][0] += w0 * fav.x; acc[0][1] += w0 * fav.y;
      acc[0][2] += w0 * fav.z; acc[0][3] += w0 * fav.w;
      acc[1][0] += w1 * fav.x; acc[1][1] += w1 * fav.y;
      acc[1][2] += w1 * fav.z; acc[1][3] += w1 * fav.w;
    }
    float partv = 0.f;
#pragma unroll
    for (int r = 0; r < 2; ++r)
#pragma unroll
      for (int j = 0; j < 4; ++j) {
        float a = acc[r][j] + s_reg[r][j] * v_reg[r][j];  // + identity
        float nvv = v_reg[r][j] - s_reg[r][j] * a;        // (Lv)
        nv[r][j] = nvv;
        partv += (it < 3) ? nvv * nvv : v_reg[r][j] * nvv;
      }
    for (int o = 32; o > 0; o >>= 1) partv += __shfl_down(partv, o, 64);
    if (lane == 0) red[wvi] = partv;
    __syncthreads();
    float total = 0.f;
#pragma unroll
    for (int i2 = 0; i2 < 8; ++i2) total += red[i2];  // redundant, broadcast
    if (it < 3) {
      float inv = 1.0f / (sqrtf(total) + 1e-10f);
#pragma unroll
      for (int r = 0; r < 2; ++r) {
        int row = t + 64 * r;
        float w[4];
#pragma unroll
        for (int j = 0; j < 4; ++j) {
          v_reg[r][j] = nv[r][j] * inv;
          w[j] = s_reg[r][j] * v_reg[r][j];
        }
        *(float4*)&bufRow[row * WS36 + f0] = make_float4(w[0], w[1], w[2], w[3]);
#pragma unroll
        for (int j = 0; j < 4; ++j) bufT[(f0 + j) * TS + row] = w[j];
      }
      __syncthreads();
    } else {
      snv = fmaxf(fabsf(total), 1.0f);
    }
  }
  const float csn = 2.0f / snv;
  const float cm1 = csn - 1.0f;

  // ============ phase 5: stage x (regs -> Zs/ZT/XT) ============
  {
#pragma unroll
    for (int half = 0; half < 2; ++half) {
      const int row = xrow0 + 64 * half;
      const float4 xv = half ? xv4b : xv4a;
      float rrow = rsT[row];
      float s0 = 1.0f / sqrtf(rrow + rsF[4 * xc4 + 0] + 1.0f + 1e-10f);
      float s1 = 1.0f / sqrtf(rrow + rsF[4 * xc4 + 1] + 1.0f + 1e-10f);
      float s2 = 1.0f / sqrtf(rrow + rsF[4 * xc4 + 2] + 1.0f + 1e-10f);
      float s3 = 1.0f / sqrtf(rrow + rsF[4 * xc4 + 3] + 1.0f + 1e-10f);
      float4 zv = make_float4(xv.x * s0, xv.y * s1, xv.z * s2, xv.w * s3);
      *(float4*)&bufRow[row * WS36 + 4 * xc4] = zv;
      XT[(4 * xc4 + 0) * TS + row] = xv.x; bufT[(4 * xc4 + 0) * TS + row] = zv.x;
      XT[(4 * xc4 + 1) * TS + row] = xv.y; bufT[(4 * xc4 + 1) * TS + row] = zv.y;
      XT[(4 * xc4 + 2) * TS + row] = xv.z; bufT[(4 * xc4 + 2) * TS + row] = zv.z;
      XT[(4 * xc4 + 3) * TS + row] = xv.w; bufT[(4 * xc4 + 3) * TS + row] = zv.w;
    }
  }
  __syncthreads();

  // ============ phase 6: G = (c-1)X - c*s.*(ta^T Z + Z fa + Z) ============
  // 8 features/thread: t2 = tid&127 (lanes), fg = 8*(tid>>7) in {0,8,16,24}
  const int t2 = tid & 127, fg = 8 * (tid >> 7);
  float greg[8];
  {
    float acc[8] = {};
    if (flagS) {  // rare path: dense ta column reads (lane-consecutive)
      for (int k = 0; k < Tc; ++k) {
        float ta0 = taL[k * TAS + t2];
        float4 z0 = *(const float4*)&bufRow[k * WS36 + fg];      // broadcast
        float4 z1 = *(const float4*)&bufRow[k * WS36 + fg + 4];  // broadcast
        acc[0] += ta0 * z0.x; acc[1] += ta0 * z0.y;
        acc[2] += ta0 * z0.z; acc[3] += ta0 * z0.w;
        acc[4] += ta0 * z1.x; acc[5] += ta0 * z1.y;
        acc[6] += ta0 * z1.z; acc[7] += ta0 * z1.w;
      }
    }
    for (int f2 = 0; f2 < Fc; ++f2) {
      float4 fa0 = *(const float4*)&faS[f2 * WS36 + fg];      // broadcast
      float4 fa1 = *(const float4*)&faS[f2 * WS36 + fg + 4];  // broadcast
      float zt0 = bufT[f2 * TS + t2];                         // lane-consecutive
      acc[0] += zt0 * fa0.x; acc[1] += zt0 * fa0.y;
      acc[2] += zt0 * fa0.z; acc[3] += zt0 * fa0.w;
      acc[4] += zt0 * fa1.x; acc[5] += zt0 * fa1.y;
      acc[6] += zt0 * fa1.z; acc[7] += zt0 * fa1.w;
    }
    float rrow = rsT[t2];
#pragma unroll
    for (int j = 0; j < 8; ++j) {
      int f = fg + j;
      float xvv = XT[f * TS + t2];
      float zvv = bufT[f * TS + t2];
      float sv = 1.0f / sqrtf(rrow + rsF[f] + 1.0f + 1e-10f);
      greg[j] = cm1 * xvv - csn * sv * (acc[j] + zvv);
    }
  }
  __syncthreads();  // all reads of bufRow (Zs) complete
#pragma unroll
  for (int j = 0; j < 8; ++j) bufRow[(fg + j) * TS + t2] = greg[j];  // GT
  __syncthreads();

  // ============ phase 7: out = X@W0 + G@W1 + bias ============
  {
    const int hd0 = 4 * (tid >> 7);  // {0,4,8,12} — covers HDc=16
    float acc2[4] = {};
    for (int f = 0; f < Fc; ++f) {
      float4 w0 = *(const float4*)&W0s[f * HDc + hd0];  // broadcast
      float4 w1 = *(const float4*)&W1s[f * HDc + hd0];  // broadcast
      float xvv = XT[f * TS + t2];
      float gvv = bufRow[f * TS + t2];
      acc2[0] += xvv * w0.x + gvv * w1.x;
      acc2[1] += xvv * w0.y + gvv * w1.y;
      acc2[2] += xvv * w0.z + gvv * w1.z;
      acc2[3] += xvv * w0.w + gvv * w1.w;
    }
    float4 bv = *(const float4*)&bias[h * HDc + hd0];
    float4 o4 = make_float4(acc2[0] + bv.x, acc2[1] + bv.y,
                            acc2[2] + bv.z, acc2[3] + bv.w);
    *(float4*)&out[((size_t)b * Tc + t2) * (Hc * HDc) + h * HDc + hd0] = o4;
  }
}

extern "C" void kernel_launch(void* const* d_in, const int* in_sizes, int n_in,
                              void* d_out, int out_size, void* d_ws, size_t ws_size,
                              hipStream_t stream) {
  const float* x      = (const float*)d_in[0];
  const float* weight = (const float*)d_in[1];
  const float* bias   = (const float*)d_in[2];
  const float* tqg    = (const float*)d_in[3];
  const float* tkg    = (const float*)d_in[4];
  const float* ffg    = (const float*)d_in[5];
  float* out = (float*)d_out;

  fused_all_kernel<<<dim3(Bc, Hc), dim3(512), 0, stream>>>(
      x, weight, bias, tqg, tkg, ffg, out);
}

// Round 13
// 45.381 us; speedup vs baseline: 1.2476x; 1.2476x over previous
//
#include <hip/hip_runtime.h>
#include <cstdint>

static constexpr int Bc = 32, Tc = 128, Fc = 32, Hc = 4, HDc = 16, RKc = 16;
static constexpr int Nc = Tc * Fc;  // 4096
static constexpr int WS36 = 36;     // padded [*][32] stride

__device__ __forceinline__ uint32_t rotl32(uint32_t v, int r) {
  return (v << r) | (v >> (32 - r));
}

__device__ __forceinline__ void threefry2x32(uint32_t k0, uint32_t k1,
                                             uint32_t& x0, uint32_t& x1) {
  uint32_t k2 = k0 ^ k1 ^ 0x1BD11BDAu;
  x0 += k0; x1 += k1;
#define TF_R(r) { x0 += x1; x1 = rotl32(x1, (r)); x1 ^= x0; }
  TF_R(13) TF_R(15) TF_R(26) TF_R(6)
  x0 += k1; x1 += k2 + 1u;
  TF_R(17) TF_R(29) TF_R(16) TF_R(24)
  x0 += k2; x1 += k0 + 2u;
  TF_R(13) TF_R(15) TF_R(26) TF_R(6)
  x0 += k0; x1 += k1 + 3u;
  TF_R(17) TF_R(29) TF_R(16) TF_R(24)
  x0 += k1; x1 += k2 + 4u;
  TF_R(13) TF_R(15) TF_R(26) TF_R(6)
  x0 += k2; x1 += k0 + 5u;
#undef TF_R
}

__device__ __forceinline__ float erfinv_f32(float x) {
  float w = -__logf((1.0f - x) * (1.0f + x));
  float p;
  if (w < 5.0f) {
    w -= 2.5f;
    p = 2.81022636e-08f;
    p = fmaf(p, w, 3.43273939e-07f);
    p = fmaf(p, w, -3.5233877e-06f);
    p = fmaf(p, w, -4.39150654e-06f);
    p = fmaf(p, w, 0.00021858087f);
    p = fmaf(p, w, -0.00125372503f);
    p = fmaf(p, w, -0.00417768164f);
    p = fmaf(p, w, 0.246640727f);
    p = fmaf(p, w, 1.50140941f);
  } else {
    w = sqrtf(w) - 3.0f;
    p = -0.000200214257f;
    p = fmaf(p, w, 0.000100950558f);
    p = fmaf(p, w, 0.00134934322f);
    p = fmaf(p, w, -0.00367342844f);
    p = fmaf(p, w, 0.00573950773f);
    p = fmaf(p, w, -0.0076224613f);
    p = fmaf(p, w, 0.00943887047f);
    p = fmaf(p, w, 1.00167406f);
    p = fmaf(p, w, 2.83297682f);
  }
  return p * x;
}

__device__ __forceinline__ float jax_normal_from_bits(uint32_t bits) {
  const float lo = -0.99999994f;
  float f = __uint_as_float((bits >> 9) | 0x3f800000u) - 1.0f;
  float u = fmaxf(lo, f * 2.0f + lo);
  return 1.41421354f * erfinv_f32(u);
}

// ---------------------------------------------------------------------------
// K1: scores + row softmax + threshold -> dense ta + rs. grid (h, chunk=8),
// 512 threads. (R8's proven kernel, CSR machinery removed.)
// ---------------------------------------------------------------------------
__global__ __launch_bounds__(512)
void score_kernel(const float* __restrict__ x, const float* __restrict__ weight,
                  const float* __restrict__ tqg, const float* __restrict__ tkg,
                  float* __restrict__ ws_ta, float* __restrict__ ws_rs) {
  const int h = blockIdx.x, chunk = blockIdx.y;
  const int tid = (int)threadIdx.x;
  __shared__ float kS[Bc][Tc];
  __shared__ float qS[Bc][16];
  __shared__ float wqv[Fc], wkv[Fc];

  if (tid < Fc) {
    const float* W0 = weight + h * (Fc * HDc);
    float aq = 0.f, ak = 0.f;
    for (int d = 0; d < HDc; ++d) {
      float w0 = W0[tid * HDc + d];
      aq += w0 * tqg[h * HDc + d];
      ak += w0 * tkg[h * HDc + d];
    }
    wqv[tid] = aq; wkv[tid] = ak;
  }
  __syncthreads();

  for (int i = tid; i < Bc * Tc; i += 512) {
    const float4* xr = (const float4*)(x + (size_t)i * Fc);
    float ak = 0.f;
#pragma unroll
    for (int j = 0; j < 8; ++j) {
      float4 v = xr[j];
      ak += v.x * wkv[4*j] + v.y * wkv[4*j+1] + v.z * wkv[4*j+2] + v.w * wkv[4*j+3];
    }
    kS[i >> 7][i & 127] = ak;
  }
  {
    int b = tid >> 4, tt = tid & 15;
    const float4* xr = (const float4*)(x + ((size_t)b * Tc + 16 * chunk + tt) * Fc);
    float aq = 0.f;
#pragma unroll
    for (int j = 0; j < 8; ++j) {
      float4 v = xr[j];
      aq += v.x * wqv[4*j] + v.y * wqv[4*j+1] + v.z * wqv[4*j+2] + v.w * wqv[4*j+3];
    }
    qS[b][tt] = aq;
  }
  __syncthreads();

  const int t1l = tid >> 5, t2q = tid & 31;
  const int gt1 = 16 * chunk + t1l;
  float acc[4] = {};
  for (int b = 0; b < Bc; ++b) {
    float q = qS[b][t1l];
    float4 k4 = *(const float4*)&kS[b][4 * t2q];
    float kv[4] = {k4.x, k4.y, k4.z, k4.w};
#pragma unroll
    for (int j = 0; j < 4; ++j) {
      float s = q + kv[j];
      acc[j] += fmaxf(s, 0.2f * s);
    }
  }
#pragma unroll
  for (int j = 0; j < 4; ++j) acc[j] *= (1.0f / 32.0f);

  float m = fmaxf(fmaxf(acc[0], acc[1]), fmaxf(acc[2], acc[3]));
  for (int o = 16; o > 0; o >>= 1) m = fmaxf(m, __shfl_xor(m, o, 32));
  float e[4], se = 0.f;
#pragma unroll
  for (int j = 0; j < 4; ++j) { e[j] = expf(acc[j] - m); se += e[j]; }
  for (int o = 16; o > 0; o >>= 1) se += __shfl_xor(se, o, 32);
  float p[4]; float rs = 0.f;
#pragma unroll
  for (int j = 0; j < 4; ++j) {
    float pv = e[j] / se;
    int col = 4 * t2q + j;
    p[j] = ((pv > 0.01f) && (col != gt1)) ? pv : 0.f;
    rs += p[j];
  }
  for (int o = 16; o > 0; o >>= 1) rs += __shfl_xor(rs, o, 32);

  float* tar = ws_ta + (size_t)h * (Tc * Tc) + (size_t)gt1 * Tc + 4 * t2q;
  *(float4*)tar = make_float4(p[0], p[1], p[2], p[3]);
  if (t2q == 0) ws_rs[h * Tc + gt1] = rs;
}

// ---------------------------------------------------------------------------
// K2: conv, grid (b, h) = 128 blocks, 512 threads.
// thread = (t = tid>>2, fq = tid&3): owns row t's 8-feature quarter.
// With ta==0 (common case, flag from rs): L is block-diagonal over t ->
// power iteration is register+shfl only, NO normalization (factored out),
// only 2 barriers in the whole kernel. flag=1 keeps an LDS/global fallback.
// ---------------------------------------------------------------------------
__global__ __launch_bounds__(512, 1)
void conv_kernel(const float* __restrict__ x, const float* __restrict__ weight,
                 const float* __restrict__ bias, const float* __restrict__ ffg,
                 const float* __restrict__ ws_ta, const float* __restrict__ ws_rs,
                 float* __restrict__ out) {
  const int b = blockIdx.x, h = blockIdx.y;
  const int tid = (int)threadIdx.x;
  const int lane = tid & 63, wvi = tid >> 6;

  __shared__ __align__(16) float faS[Fc * WS36];   // fa[f1][f2]
  __shared__ __align__(16) float faTS[Fc * WS36];  // faT[f2][f1]
  __shared__ __align__(16) float W0s[Fc * HDc];
  __shared__ __align__(16) float W1s[Fc * HDc];
  __shared__ __align__(16) float vtmp[Nc];         // PRNG exchange
  __shared__ __align__(16) float wbuf[Tc * WS36];  // flag-path rows
  __shared__ float rsT[Tc], rsF[Fc];
  __shared__ float red[8][2];
  __shared__ int flagS;

  const int t = tid >> 2, fq = tid & 3, f0 = 4 * fq * 2;  // f0 = 8*fq

  if (tid < Tc) rsT[tid] = ws_rs[h * Tc + tid];
  { // weights
    W0s[tid] = weight[h * (Fc * HDc) + tid];
    W1s[tid] = weight[(Hc + h) * (Fc * HDc) + tid];
  }
  // flag from global rs (no LDS dependency)
  if (tid < 64) {
    int nz = (ws_rs[h * Tc + tid] > 0.f) || (ws_rs[h * Tc + tid + 64] > 0.f);
    unsigned long long bal = __ballot(nz);
    if (tid == 0) flagS = (bal != 0ull) ? 1 : 0;
  }
  // x row quarter -> registers (coalesced: 32B/lane)
  const float* xb = x + (size_t)b * Nc;
  float4 xva = *(const float4*)&xb[t * Fc + f0];
  float4 xvb = *(const float4*)&xb[t * Fc + f0 + 4];

  // fa = threshold(softmax(leaky_relu(U V^T), axis=1)); 2 cells/thread
  for (int j2 = tid; j2 < Fc * Fc; j2 += 512) {
    const float* U = ffg + h * (2 * Fc * RKc);
    const float* V = U + Fc * RKc;
    int f1 = j2 >> 5, f2 = j2 & 31;
    float acc = 0.f;
    for (int r = 0; r < RKc; ++r) acc += U[f1 * RKc + r] * V[f2 * RKc + r];
    float val = fmaxf(acc, 0.2f * acc);
    float m = val;
    for (int o = 16; o > 0; o >>= 1) m = fmaxf(m, __shfl_xor(m, o, 32));
    float e = expf(val - m), se = e;
    for (int o = 16; o > 0; o >>= 1) se += __shfl_xor(se, o, 32);
    float pv = e / se;
    pv = (pv > 0.01f && f1 != f2) ? pv : 0.f;
    faS[f1 * WS36 + f2] = pv;
    faTS[f2 * WS36 + f1] = pv;
    float rsum = pv;
    for (int o = 16; o > 0; o >>= 1) rsum += __shfl_xor(rsum, o, 32);
    if (f2 == 0) rsF[f1] = rsum;
  }
  // PRNG: 4 pairs/thread -> vtmp (both iota halves)
  {
    uint32_t fk0 = 0u, fk1 = (uint32_t)h;
    threefry2x32(0u, 42u, fk0, fk1);
    float n0[4], n1[4];
#pragma unroll
    for (int jj = 0; jj < 4; ++jj) {
      int l = tid * 4 + jj;  // 0..2047
      uint32_t c0 = (uint32_t)l, c1 = (uint32_t)(l + 2048);
      threefry2x32(fk0, fk1, c0, c1);
      n0[jj] = jax_normal_from_bits(c0);
      n1[jj] = jax_normal_from_bits(c1);
    }
    *(float4*)&vtmp[tid * 4]        = make_float4(n0[0], n0[1], n0[2], n0[3]);
    *(float4*)&vtmp[2048 + tid * 4] = make_float4(n1[0], n1[1], n1[2], n1[3]);
  }
  __syncthreads();  // BARRIER 1: fa/rsF/rsT/W/vtmp/flagS all visible

  // ---- per-row state in registers
  float s_reg[8], v[8];
  {
    float rrow = rsT[t];
#pragma unroll
    for (int j = 0; j < 8; ++j)
      s_reg[j] = 1.0f / sqrtf(rrow + rsF[f0 + j] + 1.0f + 1e-10f);
    float4 v0a = *(const float4*)&vtmp[t * Fc + f0];
    float4 v0b = *(const float4*)&vtmp[t * Fc + f0 + 4];
    v[0]=v0a.x; v[1]=v0a.y; v[2]=v0a.z; v[3]=v0a.w;
    v[4]=v0b.x; v[5]=v0b.y; v[6]=v0b.z; v[7]=v0b.w;
  }

  // ---- power iteration: u_{k+1} = L u_k (UNNORMALIZED; norm factored out)
  const int srcBase = lane & 60;  // (t&15)*4
  float u4[8];
  for (int it = 0; it < 4; ++it) {
    float w[8];
#pragma unroll
    for (int j = 0; j < 8; ++j) w[j] = s_reg[j] * v[j];
    if (flagS) {  // rare: publish w rows for M1
      *(float4*)&wbuf[t * WS36 + f0]     = make_float4(w[0], w[1], w[2], w[3]);
      *(float4*)&wbuf[t * WS36 + f0 + 4] = make_float4(w[4], w[5], w[6], w[7]);
      __syncthreads();
    }
    // gather full w row via shfl (own quarter included)
    float wrow[32];
#pragma unroll
    for (int oq = 0; oq < 4; ++oq)
#pragma unroll
      for (int j = 0; j < 8; ++j)
        wrow[oq * 8 + j] = __shfl(w[j], srcBase + oq, 64);
    // M2: acc[f] = sum_f2 fa[f][f2] * w[t][f2]
    float acc[8] = {};
#pragma unroll
    for (int f2 = 0; f2 < Fc; ++f2) {
      float4 fa0 = *(const float4*)&faTS[f2 * WS36 + f0];      // 4-way bcast
      float4 fa1 = *(const float4*)&faTS[f2 * WS36 + f0 + 4];
      float ww = wrow[f2];
      acc[0] += ww * fa0.x; acc[1] += ww * fa0.y;
      acc[2] += ww * fa0.z; acc[3] += ww * fa0.w;
      acc[4] += ww * fa1.x; acc[5] += ww * fa1.y;
      acc[6] += ww * fa1.z; acc[7] += ww * fa1.w;
    }
    if (flagS) {  // M1: sum_k ta[t][k] * w[k][f]
      const float* taG = ws_ta + (size_t)h * (Tc * Tc) + (size_t)t * Tc;
      for (int k = 0; k < Tc; ++k) {
        float tak = taG[k];
        float4 w0 = *(const float4*)&wbuf[k * WS36 + f0];
        float4 w1 = *(const float4*)&wbuf[k * WS36 + f0 + 4];
        acc[0] += tak * w0.x; acc[1] += tak * w0.y;
        acc[2] += tak * w0.z; acc[3] += tak * w0.w;
        acc[4] += tak * w1.x; acc[5] += tak * w1.y;
        acc[6] += tak * w1.z; acc[7] += tak * w1.w;
      }
      __syncthreads();  // before next iter's wbuf overwrite
    }
    float nv[8];
#pragma unroll
    for (int j = 0; j < 8; ++j) {
      float a = acc[j] + w[j];           // + identity part of adj
      nv[j] = v[j] - s_reg[j] * a;       // (L u)[t,f]
    }
    if (it < 3) {
#pragma unroll
      for (int j = 0; j < 8; ++j) v[j] = nv[j];
    } else {
#pragma unroll
      for (int j = 0; j < 8; ++j) u4[j] = nv[j];  // v stays u3
    }
  }
  // Rayleigh: sn = |u3.u4| / ||u3||^2
  {
    float pn = 0.f, pd = 0.f;
#pragma unroll
    for (int j = 0; j < 8; ++j) { pn += v[j] * u4[j]; pd += v[j] * v[j]; }
    for (int o = 32; o > 0; o >>= 1) {
      pn += __shfl_down(pn, o, 64);
      pd += __shfl_down(pd, o, 64);
    }
    if (lane == 0) { red[wvi][0] = pn; red[wvi][1] = pd; }
  }
  __syncthreads();  // BARRIER 2
  float num = 0.f, den = 0.f;
#pragma unroll
  for (int i2 = 0; i2 < 8; ++i2) { num += red[i2][0]; den += red[i2][1]; }
  const float sn = fmaxf(fabsf(num / den), 1.0f);
  const float csn = 2.0f / sn;
  const float cm1 = csn - 1.0f;

  // ---- conv: all row-local (flag=0). X,Z,G in registers.
  float X[8] = {xva.x, xva.y, xva.z, xva.w, xvb.x, xvb.y, xvb.z, xvb.w};
  float Z[8];
#pragma unroll
  for (int j = 0; j < 8; ++j) Z[j] = s_reg[j] * X[j];
  float gacc[8] = {};
  if (flagS) {  // rare: G1[t][f] = sum_k ta[k][t] Z[k][f]
    *(float4*)&wbuf[t * WS36 + f0]     = make_float4(Z[0], Z[1], Z[2], Z[3]);
    *(float4*)&wbuf[t * WS36 + f0 + 4] = make_float4(Z[4], Z[5], Z[6], Z[7]);
    __syncthreads();
    const float* taG = ws_ta + (size_t)h * (Tc * Tc);
    for (int k = 0; k < Tc; ++k) {
      float tak = taG[(size_t)k * Tc + t];
      float4 z0 = *(const float4*)&wbuf[k * WS36 + f0];
      float4 z1 = *(const float4*)&wbuf[k * WS36 + f0 + 4];
      gacc[0] += tak * z0.x; gacc[1] += tak * z0.y;
      gacc[2] += tak * z0.z; gacc[3] += tak * z0.w;
      gacc[4] += tak * z1.x; gacc[5] += tak * z1.y;
      gacc[6] += tak * z1.z; gacc[7] += tak * z1.w;
    }
  }
  // Z @ fa: sum_f2 Z[t][f2] * fa[f2][f]
  {
    float zrow[32];
#pragma unroll
    for (int oq = 0; oq < 4; ++oq)
#pragma unroll
      for (int j = 0; j < 8; ++j)
        zrow[oq * 8 + j] = __shfl(Z[j], srcBase + oq, 64);
#pragma unroll
    for (int f2 = 0; f2 < Fc; ++f2) {
      float4 fa0 = *(const float4*)&faS[f2 * WS36 + f0];      // fa[f2][f]
      float4 fa1 = *(const float4*)&faS[f2 * WS36 + f0 + 4];
      float zz = zrow[f2];
      gacc[0] += zz * fa0.x; gacc[1] += zz * fa0.y;
      gacc[2] += zz * fa0.z; gacc[3] += zz * fa0.w;
      gacc[4] += zz * fa1.x; gacc[5] += zz * fa1.y;
      gacc[6] += zz * fa1.z; gacc[7] += zz * fa1.w;
    }
  }
  float G[8];
#pragma unroll
  for (int j = 0; j < 8; ++j)
    G[j] = cm1 * X[j] - csn * s_reg[j] * (gacc[j] + Z[j]);

  // ---- out[t][hd] = sum_f X W0 + G W1 (partial over my 8 f, reduce over fq)
  float acc2[16] = {};
#pragma unroll
  for (int jf = 0; jf < 8; ++jf) {
    int f = f0 + jf;
#pragma unroll
    for (int hq = 0; hq < 4; ++hq) {
      float4 w0 = *(const float4*)&W0s[f * HDc + 4 * hq];  // 4-way bcast
      float4 w1 = *(const float4*)&W1s[f * HDc + 4 * hq];
      acc2[4*hq+0] += X[jf] * w0.x + G[jf] * w1.x;
      acc2[4*hq+1] += X[jf] * w0.y + G[jf] * w1.y;
      acc2[4*hq+2] += X[jf] * w0.z + G[jf] * w1.z;
      acc2[4*hq+3] += X[jf] * w0.w + G[jf] * w1.w;
    }
  }
#pragma unroll
  for (int i2 = 0; i2 < 16; ++i2) {
    acc2[i2] += __shfl_xor(acc2[i2], 1, 64);
    acc2[i2] += __shfl_xor(acc2[i2], 2, 64);
  }
  {
    float4 bv = *(const float4*)&bias[h * HDc + 4 * fq];
    float4 o4;
    if      (fq == 0) o4 = make_float4(acc2[0],  acc2[1],  acc2[2],  acc2[3]);
    else if (fq == 1) o4 = make_float4(acc2[4],  acc2[5],  acc2[6],  acc2[7]);
    else if (fq == 2) o4 = make_float4(acc2[8],  acc2[9],  acc2[10], acc2[11]);
    else              o4 = make_float4(acc2[12], acc2[13], acc2[14], acc2[15]);
    o4.x += bv.x; o4.y += bv.y; o4.z += bv.z; o4.w += bv.w;
    *(float4*)&out[((size_t)b * Tc + t) * (Hc * HDc) + h * HDc + 4 * fq] = o4;
  }
}

extern "C" void kernel_launch(void* const* d_in, const int* in_sizes, int n_in,
                              void* d_out, int out_size, void* d_ws, size_t ws_size,
                              hipStream_t stream) {
  const float* x      = (const float*)d_in[0];
  const float* weight = (const float*)d_in[1];
  const float* bias   = (const float*)d_in[2];
  const float* tqg    = (const float*)d_in[3];
  const float* tkg    = (const float*)d_in[4];
  const float* ffg    = (const float*)d_in[5];
  float* out = (float*)d_out;

  float* ws = (float*)d_ws;
  float* ws_ta = ws;            // 4*16384 = 65536
  float* ws_rs = ws + 65536;    // 512

  score_kernel<<<dim3(Hc, 8), dim3(512), 0, stream>>>(
      x, weight, tqg, tkg, ws_ta, ws_rs);
  conv_kernel<<<dim3(Bc, Hc), dim3(512), 0, stream>>>(
      x, weight, bias, ffg, ws_ta, ws_rs, out);
}

// Round 14
// 34.518 us; speedup vs baseline: 1.6402x; 1.3147x over previous
//
#include <hip/hip_runtime.h>
#include <cstdint>

static constexpr int Bc = 32, Tc = 128, Fc = 32, Hc = 4, HDc = 16, RKc = 16;
static constexpr int Nc = Tc * Fc;  // 4096
static constexpr int WS36 = 36;     // padded [*][32] stride
static constexpr int XLS = 33;      // padded x-row stride in K0

__device__ __forceinline__ uint32_t rotl32(uint32_t v, int r) {
  return (v << r) | (v >> (32 - r));
}

__device__ __forceinline__ void threefry2x32(uint32_t k0, uint32_t k1,
                                             uint32_t& x0, uint32_t& x1) {
  uint32_t k2 = k0 ^ k1 ^ 0x1BD11BDAu;
  x0 += k0; x1 += k1;
#define TF_R(r) { x0 += x1; x1 = rotl32(x1, (r)); x1 ^= x0; }
  TF_R(13) TF_R(15) TF_R(26) TF_R(6)
  x0 += k1; x1 += k2 + 1u;
  TF_R(17) TF_R(29) TF_R(16) TF_R(24)
  x0 += k2; x1 += k0 + 2u;
  TF_R(13) TF_R(15) TF_R(26) TF_R(6)
  x0 += k0; x1 += k1 + 3u;
  TF_R(17) TF_R(29) TF_R(16) TF_R(24)
  x0 += k1; x1 += k2 + 4u;
  TF_R(13) TF_R(15) TF_R(26) TF_R(6)
  x0 += k2; x1 += k0 + 5u;
#undef TF_R
}

__device__ __forceinline__ float erfinv_f32(float x) {
  float w = -__logf((1.0f - x) * (1.0f + x));
  float p;
  if (w < 5.0f) {
    w -= 2.5f;
    p = 2.81022636e-08f;
    p = fmaf(p, w, 3.43273939e-07f);
    p = fmaf(p, w, -3.5233877e-06f);
    p = fmaf(p, w, -4.39150654e-06f);
    p = fmaf(p, w, 0.00021858087f);
    p = fmaf(p, w, -0.00125372503f);
    p = fmaf(p, w, -0.00417768164f);
    p = fmaf(p, w, 0.246640727f);
    p = fmaf(p, w, 1.50140941f);
  } else {
    w = sqrtf(w) - 3.0f;
    p = -0.000200214257f;
    p = fmaf(p, w, 0.000100950558f);
    p = fmaf(p, w, 0.00134934322f);
    p = fmaf(p, w, -0.00367342844f);
    p = fmaf(p, w, 0.00573950773f);
    p = fmaf(p, w, -0.0076224613f);
    p = fmaf(p, w, 0.00943887047f);
    p = fmaf(p, w, 1.00167406f);
    p = fmaf(p, w, 2.83297682f);
  }
  return p * x;
}

__device__ __forceinline__ float jax_normal_from_bits(uint32_t bits) {
  const float lo = -0.99999994f;
  float f = __uint_as_float((bits >> 9) | 0x3f800000u) - 1.0f;
  float u = fmaxf(lo, f * 2.0f + lo);
  return 1.41421354f * erfinv_f32(u);
}

// ---------------------------------------------------------------------------
// K0: q/k projections for all heads. grid (b) = 32 blocks, 256 threads.
// Stages x[b] (16 KB, coalesced) in padded LDS; computes q,k[h][b][t] -> ws.
// ---------------------------------------------------------------------------
__global__ __launch_bounds__(256)
void proj_kernel(const float* __restrict__ x, const float* __restrict__ weight,
                 const float* __restrict__ tqg, const float* __restrict__ tkg,
                 float* __restrict__ ws_q, float* __restrict__ ws_k) {
  const int b = blockIdx.x;
  const int tid = (int)threadIdx.x;
  __shared__ float xL[Tc * XLS];          // padded: bank (t+f)%32
  __shared__ float wqS[Hc * Fc], wkS[Hc * Fc];

  const float* xb = x + (size_t)b * Nc;
  for (int j = tid; j < Nc / 4; j += 256) {
    int row = j >> 3, c4 = j & 7;
    float4 v = *(const float4*)&xb[row * Fc + 4 * c4];
    xL[row * XLS + 4 * c4 + 0] = v.x;
    xL[row * XLS + 4 * c4 + 1] = v.y;
    xL[row * XLS + 4 * c4 + 2] = v.z;
    xL[row * XLS + 4 * c4 + 3] = v.w;
  }
  if (tid < Hc * Fc) {
    int h = tid >> 5, f = tid & 31;
    const float* W0 = weight + h * (Fc * HDc) + f * HDc;
    float aq = 0.f, ak = 0.f;
    for (int d = 0; d < HDc; ++d) {
      aq += W0[d] * tqg[h * HDc + d];
      ak += W0[d] * tkg[h * HDc + d];
    }
    wqS[tid] = aq; wkS[tid] = ak;
  }
  __syncthreads();

  const int h = tid >> 6, lane = tid & 63;
#pragma unroll
  for (int half = 0; half < 2; ++half) {
    int t = lane + 64 * half;
    float aq = 0.f, ak = 0.f;
    for (int f = 0; f < Fc; ++f) {
      float xv = xL[t * XLS + f];        // conflict-free (t+f)%32
      aq += xv * wqS[h * Fc + f];        // wave-uniform broadcast
      ak += xv * wkS[h * Fc + f];
    }
    ws_q[h * Nc + b * Tc + t] = aq;
    ws_k[h * Nc + b * Tc + t] = ak;
  }
}

// ---------------------------------------------------------------------------
// K1: scores + row softmax + threshold -> dense ta + rs.
// grid (h, chunk=32 of 4 rows), 256 threads. Reads q/k from ws.
// thread = (r = tid>>6 in 0..3, lane): cols {lane, lane+64}.
// ---------------------------------------------------------------------------
__global__ __launch_bounds__(256)
void score_kernel(const float* __restrict__ ws_q, const float* __restrict__ ws_k,
                  float* __restrict__ ws_ta, float* __restrict__ ws_rs) {
  const int h = blockIdx.x, chunk = blockIdx.y;
  const int tid = (int)threadIdx.x;
  __shared__ float kS[Bc * Tc];   // [b][t] 16 KB
  __shared__ float qS[Bc * 4];    // [b][r]

  for (int j = tid; j < Bc * Tc / 4; j += 256)
    ((float4*)kS)[j] = ((const float4*)(ws_k + (size_t)h * Nc))[j];
  if (tid < Bc * 4) {
    int b = tid >> 2, r = tid & 3;
    qS[tid] = ws_q[(size_t)h * Nc + b * Tc + 4 * chunk + r];
  }
  __syncthreads();

  const int r = tid >> 6, lane = tid & 63;
  const int gr = 4 * chunk + r;
  float acc0 = 0.f, acc1 = 0.f;
  for (int b = 0; b < Bc; ++b) {
    float q = qS[b * 4 + r];             // broadcast
    float k0 = kS[b * Tc + lane];        // lane-consecutive
    float k1 = kS[b * Tc + lane + 64];
    float s0 = q + k0, s1 = q + k1;
    acc0 += fmaxf(s0, 0.2f * s0);
    acc1 += fmaxf(s1, 0.2f * s1);
  }
  acc0 *= (1.0f / 32.0f);
  acc1 *= (1.0f / 32.0f);

  float m = fmaxf(acc0, acc1);
  for (int o = 32; o > 0; o >>= 1) m = fmaxf(m, __shfl_xor(m, o, 64));
  float e0 = expf(acc0 - m), e1 = expf(acc1 - m);
  float se = e0 + e1;
  for (int o = 32; o > 0; o >>= 1) se += __shfl_xor(se, o, 64);
  float p0 = e0 / se, p1 = e1 / se;
  p0 = ((p0 > 0.01f) && (lane != gr)) ? p0 : 0.f;
  p1 = ((p1 > 0.01f) && (lane + 64 != gr)) ? p1 : 0.f;
  float rs = p0 + p1;
  for (int o = 32; o > 0; o >>= 1) rs += __shfl_xor(rs, o, 64);

  float* tar = ws_ta + (size_t)h * (Tc * Tc) + (size_t)gr * Tc;
  tar[lane] = p0;
  tar[lane + 64] = p1;
  if (lane == 0) ws_rs[h * Tc + gr] = rs;
}

// ---------------------------------------------------------------------------
// K2: conv, grid (b, h) = 128 blocks, 512 threads. (R13 verbatim — proven.)
// thread = (t = tid>>2, fq = tid&3): owns row t's 8-feature quarter.
// ---------------------------------------------------------------------------
__global__ __launch_bounds__(512, 1)
void conv_kernel(const float* __restrict__ x, const float* __restrict__ weight,
                 const float* __restrict__ bias, const float* __restrict__ ffg,
                 const float* __restrict__ ws_ta, const float* __restrict__ ws_rs,
                 float* __restrict__ out) {
  const int b = blockIdx.x, h = blockIdx.y;
  const int tid = (int)threadIdx.x;
  const int lane = tid & 63, wvi = tid >> 6;

  __shared__ __align__(16) float faS[Fc * WS36];   // fa[f1][f2]
  __shared__ __align__(16) float faTS[Fc * WS36];  // faT[f2][f1]
  __shared__ __align__(16) float W0s[Fc * HDc];
  __shared__ __align__(16) float W1s[Fc * HDc];
  __shared__ __align__(16) float vtmp[Nc];         // PRNG exchange
  __shared__ __align__(16) float wbuf[Tc * WS36];  // flag-path rows
  __shared__ float rsT[Tc], rsF[Fc];
  __shared__ float red[8][2];
  __shared__ int flagS;

  const int t = tid >> 2, fq = tid & 3, f0 = 8 * fq;

  if (tid < Tc) rsT[tid] = ws_rs[h * Tc + tid];
  {
    W0s[tid] = weight[h * (Fc * HDc) + tid];
    W1s[tid] = weight[(Hc + h) * (Fc * HDc) + tid];
  }
  if (tid < 64) {
    int nz = (ws_rs[h * Tc + tid] > 0.f) || (ws_rs[h * Tc + tid + 64] > 0.f);
    unsigned long long bal = __ballot(nz);
    if (tid == 0) flagS = (bal != 0ull) ? 1 : 0;
  }
  const float* xb = x + (size_t)b * Nc;
  float4 xva = *(const float4*)&xb[t * Fc + f0];
  float4 xvb = *(const float4*)&xb[t * Fc + f0 + 4];

  for (int j2 = tid; j2 < Fc * Fc; j2 += 512) {
    const float* U = ffg + h * (2 * Fc * RKc);
    const float* V = U + Fc * RKc;
    int f1 = j2 >> 5, f2 = j2 & 31;
    float acc = 0.f;
    for (int r = 0; r < RKc; ++r) acc += U[f1 * RKc + r] * V[f2 * RKc + r];
    float val = fmaxf(acc, 0.2f * acc);
    float m = val;
    for (int o = 16; o > 0; o >>= 1) m = fmaxf(m, __shfl_xor(m, o, 32));
    float e = expf(val - m), se = e;
    for (int o = 16; o > 0; o >>= 1) se += __shfl_xor(se, o, 32);
    float pv = e / se;
    pv = (pv > 0.01f && f1 != f2) ? pv : 0.f;
    faS[f1 * WS36 + f2] = pv;
    faTS[f2 * WS36 + f1] = pv;
    float rsum = pv;
    for (int o = 16; o > 0; o >>= 1) rsum += __shfl_xor(rsum, o, 32);
    if (f2 == 0) rsF[f1] = rsum;
  }
  {
    uint32_t fk0 = 0u, fk1 = (uint32_t)h;
    threefry2x32(0u, 42u, fk0, fk1);
    float n0[4], n1[4];
#pragma unroll
    for (int jj = 0; jj < 4; ++jj) {
      int l = tid * 4 + jj;
      uint32_t c0 = (uint32_t)l, c1 = (uint32_t)(l + 2048);
      threefry2x32(fk0, fk1, c0, c1);
      n0[jj] = jax_normal_from_bits(c0);
      n1[jj] = jax_normal_from_bits(c1);
    }
    *(float4*)&vtmp[tid * 4]        = make_float4(n0[0], n0[1], n0[2], n0[3]);
    *(float4*)&vtmp[2048 + tid * 4] = make_float4(n1[0], n1[1], n1[2], n1[3]);
  }
  __syncthreads();  // BARRIER 1

  float s_reg[8], v[8];
  {
    float rrow = rsT[t];
#pragma unroll
    for (int j = 0; j < 8; ++j)
      s_reg[j] = 1.0f / sqrtf(rrow + rsF[f0 + j] + 1.0f + 1e-10f);
    float4 v0a = *(const float4*)&vtmp[t * Fc + f0];
    float4 v0b = *(const float4*)&vtmp[t * Fc + f0 + 4];
    v[0]=v0a.x; v[1]=v0a.y; v[2]=v0a.z; v[3]=v0a.w;
    v[4]=v0b.x; v[5]=v0b.y; v[6]=v0b.z; v[7]=v0b.w;
  }

  const int srcBase = lane & 60;
  float u4[8];
  for (int it = 0; it < 4; ++it) {
    float w[8];
#pragma unroll
    for (int j = 0; j < 8; ++j) w[j] = s_reg[j] * v[j];
    if (flagS) {
      *(float4*)&wbuf[t * WS36 + f0]     = make_float4(w[0], w[1], w[2], w[3]);
      *(float4*)&wbuf[t * WS36 + f0 + 4] = make_float4(w[4], w[5], w[6], w[7]);
      __syncthreads();
    }
    float wrow[32];
#pragma unroll
    for (int oq = 0; oq < 4; ++oq)
#pragma unroll
      for (int j = 0; j < 8; ++j)
        wrow[oq * 8 + j] = __shfl(w[j], srcBase + oq, 64);
    float acc[8] = {};
#pragma unroll
    for (int f2 = 0; f2 < Fc; ++f2) {
      float4 fa0 = *(const float4*)&faTS[f2 * WS36 + f0];
      float4 fa1 = *(const float4*)&faTS[f2 * WS36 + f0 + 4];
      float ww = wrow[f2];
      acc[0] += ww * fa0.x; acc[1] += ww * fa0.y;
      acc[2] += ww * fa0.z; acc[3] += ww * fa0.w;
      acc[4] += ww * fa1.x; acc[5] += ww * fa1.y;
      acc[6] += ww * fa1.z; acc[7] += ww * fa1.w;
    }
    if (flagS) {
      const float* taG = ws_ta + (size_t)h * (Tc * Tc) + (size_t)t * Tc;
      for (int k = 0; k < Tc; ++k) {
        float tak = taG[k];
        float4 w0 = *(const float4*)&wbuf[k * WS36 + f0];
        float4 w1 = *(const float4*)&wbuf[k * WS36 + f0 + 4];
        acc[0] += tak * w0.x; acc[1] += tak * w0.y;
        acc[2] += tak * w0.z; acc[3] += tak * w0.w;
        acc[4] += tak * w1.x; acc[5] += tak * w1.y;
        acc[6] += tak * w1.z; acc[7] += tak * w1.w;
      }
      __syncthreads();
    }
    float nv[8];
#pragma unroll
    for (int j = 0; j < 8; ++j) {
      float a = acc[j] + w[j];
      nv[j] = v[j] - s_reg[j] * a;
    }
    if (it < 3) {
#pragma unroll
      for (int j = 0; j < 8; ++j) v[j] = nv[j];
    } else {
#pragma unroll
      for (int j = 0; j < 8; ++j) u4[j] = nv[j];
    }
  }
  {
    float pn = 0.f, pd = 0.f;
#pragma unroll
    for (int j = 0; j < 8; ++j) { pn += v[j] * u4[j]; pd += v[j] * v[j]; }
    for (int o = 32; o > 0; o >>= 1) {
      pn += __shfl_down(pn, o, 64);
      pd += __shfl_down(pd, o, 64);
    }
    if (lane == 0) { red[wvi][0] = pn; red[wvi][1] = pd; }
  }
  __syncthreads();  // BARRIER 2
  float num = 0.f, den = 0.f;
#pragma unroll
  for (int i2 = 0; i2 < 8; ++i2) { num += red[i2][0]; den += red[i2][1]; }
  const float sn = fmaxf(fabsf(num / den), 1.0f);
  const float csn = 2.0f / sn;
  const float cm1 = csn - 1.0f;

  float X[8] = {xva.x, xva.y, xva.z, xva.w, xvb.x, xvb.y, xvb.z, xvb.w};
  float Z[8];
#pragma unroll
  for (int j = 0; j < 8; ++j) Z[j] = s_reg[j] * X[j];
  float gacc[8] = {};
  if (flagS) {
    *(float4*)&wbuf[t * WS36 + f0]     = make_float4(Z[0], Z[1], Z[2], Z[3]);
    *(float4*)&wbuf[t * WS36 + f0 + 4] = make_float4(Z[4], Z[5], Z[6], Z[7]);
    __syncthreads();
    const float* taG = ws_ta + (size_t)h * (Tc * Tc);
    for (int k = 0; k < Tc; ++k) {
      float tak = taG[(size_t)k * Tc + t];
      float4 z0 = *(const float4*)&wbuf[k * WS36 + f0];
      float4 z1 = *(const float4*)&wbuf[k * WS36 + f0 + 4];
      gacc[0] += tak * z0.x; gacc[1] += tak * z0.y;
      gacc[2] += tak * z0.z; gacc[3] += tak * z0.w;
      gacc[4] += tak * z1.x; gacc[5] += tak * z1.y;
      gacc[6] += tak * z1.z; gacc[7] += tak * z1.w;
    }
  }
  {
    float zrow[32];
#pragma unroll
    for (int oq = 0; oq < 4; ++oq)
#pragma unroll
      for (int j = 0; j < 8; ++j)
        zrow[oq * 8 + j] = __shfl(Z[j], srcBase + oq, 64);
#pragma unroll
    for (int f2 = 0; f2 < Fc; ++f2) {
      float4 fa0 = *(const float4*)&faS[f2 * WS36 + f0];
      float4 fa1 = *(const float4*)&faS[f2 * WS36 + f0 + 4];
      float zz = zrow[f2];
      gacc[0] += zz * fa0.x; gacc[1] += zz * fa0.y;
      gacc[2] += zz * fa0.z; gacc[3] += zz * fa0.w;
      gacc[4] += zz * fa1.x; gacc[5] += zz * fa1.y;
      gacc[6] += zz * fa1.z; gacc[7] += zz * fa1.w;
    }
  }
  float G[8];
#pragma unroll
  for (int j = 0; j < 8; ++j)
    G[j] = cm1 * X[j] - csn * s_reg[j] * (gacc[j] + Z[j]);

  float acc2[16] = {};
#pragma unroll
  for (int jf = 0; jf < 8; ++jf) {
    int f = f0 + jf;
#pragma unroll
    for (int hq = 0; hq < 4; ++hq) {
      float4 w0 = *(const float4*)&W0s[f * HDc + 4 * hq];
      float4 w1 = *(const float4*)&W1s[f * HDc + 4 * hq];
      acc2[4*hq+0] += X[jf] * w0.x + G[jf] * w1.x;
      acc2[4*hq+1] += X[jf] * w0.y + G[jf] * w1.y;
      acc2[4*hq+2] += X[jf] * w0.z + G[jf] * w1.z;
      acc2[4*hq+3] += X[jf] * w0.w + G[jf] * w1.w;
    }
  }
#pragma unroll
  for (int i2 = 0; i2 < 16; ++i2) {
    acc2[i2] += __shfl_xor(acc2[i2], 1, 64);
    acc2[i2] += __shfl_xor(acc2[i2], 2, 64);
  }
  {
    float4 bv = *(const float4*)&bias[h * HDc + 4 * fq];
    float4 o4;
    if      (fq == 0) o4 = make_float4(acc2[0],  acc2[1],  acc2[2],  acc2[3]);
    else if (fq == 1) o4 = make_float4(acc2[4],  acc2[5],  acc2[6],  acc2[7]);
    else if (fq == 2) o4 = make_float4(acc2[8],  acc2[9],  acc2[10], acc2[11]);
    else              o4 = make_float4(acc2[12], acc2[13], acc2[14], acc2[15]);
    o4.x += bv.x; o4.y += bv.y; o4.z += bv.z; o4.w += bv.w;
    *(float4*)&out[((size_t)b * Tc + t) * (Hc * HDc) + h * HDc + 4 * fq] = o4;
  }
}

extern "C" void kernel_launch(void* const* d_in, const int* in_sizes, int n_in,
                              void* d_out, int out_size, void* d_ws, size_t ws_size,
                              hipStream_t stream) {
  const float* x      = (const float*)d_in[0];
  const float* weight = (const float*)d_in[1];
  const float* bias   = (const float*)d_in[2];
  const float* tqg    = (const float*)d_in[3];
  const float* tkg    = (const float*)d_in[4];
  const float* ffg    = (const float*)d_in[5];
  float* out = (float*)d_out;

  float* ws = (float*)d_ws;
  float* ws_ta = ws;            // 4*16384 = 65536
  float* ws_rs = ws + 65536;    // 512
  float* ws_q  = ws + 66048;    // 16384
  float* ws_k  = ws + 82432;    // 16384

  proj_kernel<<<dim3(Bc), dim3(256), 0, stream>>>(
      x, weight, tqg, tkg, ws_q, ws_k);
  score_kernel<<<dim3(Hc, 32), dim3(256), 0, stream>>>(
      ws_q, ws_k, ws_ta, ws_rs);
  conv_kernel<<<dim3(Bc, Hc), dim3(512), 0, stream>>>(
      x, weight, bias, ffg, ws_ta, ws_rs, out);
}